// Round 4
// baseline (396.641 us; speedup 1.0000x reference)
//
#include <hip/hip_runtime.h>

// RGATConv x2 (N=50000, E=800000, IN=HID=128, R=8) for MI355X/gfx950.
//
// Round-12: xt ELIMINATED. Using out[d] = sum_r (sum_{e in rel r} a_e x_s) W_r,
// the aggregate kernel accumulates y[8][128] per dst from raw x (bf16, 12.8MB
// L2/L3-resident) with a wave-uniform switch on the edge relation, stages y in
// 33KB LDS (16 nodes/block), then applies all W_r as one K=1024 MFMA GEMM
// (Wb layout already the right fragments, conventions verified rounds 9-11).
// Kills k_gemm_xt (2x51.5us, 103MB write each) -> thin k_sqk (sq/sk + x->bf16
// cast). Sort chain and preps unchanged.

typedef unsigned short u16;
typedef __attribute__((ext_vector_type(8))) short short8;
typedef __attribute__((ext_vector_type(4))) float floatx4;
typedef __attribute__((ext_vector_type(4))) float float4v;

__device__ __forceinline__ u16 f2bf(float f) {
  union { float f; unsigned u; } v; v.f = f;
  unsigned r = v.u + 0x7FFFu + ((v.u >> 16) & 1u);  // RNE
  return (u16)(r >> 16);
}
__device__ __forceinline__ float bflo(unsigned v) {
  union { unsigned u; float f; } c; c.u = v << 16; return c.f;
}
__device__ __forceinline__ float bfhi(unsigned v) {
  union { unsigned u; float f; } c; c.u = v & 0xffff0000u; return c.f;
}

// ---- 1. pack stacked W into fragment order (per graph) ----------------------
// Wb[(kkg*8 + nt)*512 + lane*8 + j] = W[kkg*32 + (lane>>4)*8 + j][nt*16 + (lane&15)]
// over the stacked [R*128][128] weight (kkg = global K/32 index, 0..31).
// Valid as A-fragment of W^T for the K=1024 GEMM (rows = out-ch).
__global__ void k_prep_wb(const float* __restrict__ W1, const float* __restrict__ W2,
                          u16* __restrict__ Wb, int KK) {
  int t = blockIdx.x * 256 + threadIdx.x;
  int lane = t & 63, nt = (t >> 6) & 7, kk = t >> 9;
  if (kk >= KK) return;
  const float* W = blockIdx.y ? W2 : W1;
  u16* out = Wb + (size_t)blockIdx.y * KK * 4096;
  int q = lane >> 4, m16 = lane & 15;
  int c = nt * 16 + m16;
  short8 v;
#pragma unroll
  for (int j = 0; j < 8; ++j) {
    int k = kk * 32 + q * 8 + j;
    v[j] = (short)f2bf(W[(size_t)k * 128 + c]);
  }
  *(short8*)(out + (size_t)t * 8) = v;
}

// ---- 2. Wq[g][r][d] = sum_c W[r][d][c]*q[c]; Wk likewise --------------------
__global__ void k_prep_wqk(const float* __restrict__ W1, const float* __restrict__ q1,
                           const float* __restrict__ k1, const float* __restrict__ W2,
                           const float* __restrict__ q2, const float* __restrict__ k2,
                           float* __restrict__ Wq, float* __restrict__ Wk, int RD) {
  int wid = (blockIdx.x * 256 + threadIdx.x) >> 6;
  int lane = threadIdx.x & 63;
  if (wid >= 2 * RD) return;
  int g = wid >= RD;
  const float* W = g ? W2 : W1;
  const float* qv = g ? q2 : q1;
  const float* kv = g ? k2 : k1;
  const float* row = W + (size_t)(wid - g * RD) * 128;
  float a0 = row[lane], a1 = row[lane + 64];
  float vq = a0 * qv[lane] + a1 * qv[lane + 64];
  float vk = a0 * kv[lane] + a1 * kv[lane + 64];
#pragma unroll
  for (int off = 32; off; off >>= 1) {
    vq += __shfl_xor(vq, off);
    vk += __shfl_xor(vk, off);
  }
  if (lane == 0) { Wq[wid] = vq; Wk[wid] = vk; }
}

// ---- 3. Bqk[g][kk][lane][j]: fragment of [Wq|Wk] (16 rows/cols) -------------
__global__ void k_prep_bqk(const float* __restrict__ Wq, const float* __restrict__ Wk,
                           u16* __restrict__ Bqk, int R) {
  int total = 2 * 4 * 64 * 8;
  for (int idx = threadIdx.x; idx < total; idx += 256) {
    int j = idx & 7, lane = (idx >> 3) & 63, kk = (idx >> 9) & 3, g = idx >> 11;
    int k = kk * 32 + ((lane >> 4) & 3) * 8 + j;
    int n = lane & 15;
    float v = (n < 8) ? Wq[(g * R + n) * 128 + k] : Wk[(g * R + (n & 7)) * 128 + k];
    Bqk[idx] = f2bf(v);
  }
}

// ---- 4. [sq|sk] = x @ [Wq|Wk] via MFMA; also emit xbf = bf16(x) -------------
__global__ void __launch_bounds__(256) k_sqk(
    const float* __restrict__ x1, const float* __restrict__ x2,
    const u16* __restrict__ Bqk, u16* __restrict__ xbf,
    float* __restrict__ sq, float* __restrict__ sk, int N) {
  int g = blockIdx.y;
  const float* x = g ? x2 : x1;
  u16* xb = xbf + (size_t)g * N * 128;
  int wave = threadIdx.x >> 6, lane = threadIdx.x & 63;
  int m0 = blockIdx.x * 64 + wave * 16;
  int q = lane >> 4, m16 = lane & 15;
  int node = m0 + m16;
  int srow = (node < N) ? node : N - 1;
  short8 bfrag[4];
#pragma unroll
  for (int kk = 0; kk < 4; ++kk) {
    const float* ap = x + (size_t)srow * 128 + kk * 32 + q * 8;
    float4v f0 = *(const float4v*)ap;
    float4v f1 = *(const float4v*)(ap + 4);
    short8 a;
    a[0] = (short)f2bf(f0.x); a[1] = (short)f2bf(f0.y);
    a[2] = (short)f2bf(f0.z); a[3] = (short)f2bf(f0.w);
    a[4] = (short)f2bf(f1.x); a[5] = (short)f2bf(f1.y);
    a[6] = (short)f2bf(f1.z); a[7] = (short)f2bf(f1.w);
    bfrag[kk] = a;
  }
  if (node < N) {
#pragma unroll
    for (int kk = 0; kk < 4; ++kk)
      *(short8*)(xb + (size_t)node * 128 + kk * 32 + q * 8) = bfrag[kk];
  }
  floatx4 accq = (floatx4){0.f, 0.f, 0.f, 0.f};
#pragma unroll
  for (int kk = 0; kk < 4; ++kk) {
    short8 aq = *(const short8*)(Bqk + ((size_t)g * 4 + kk) * 512 + lane * 8);
    accq = __builtin_amdgcn_mfma_f32_16x16x32_bf16(aq, bfrag[kk], accq, 0, 0, 0);
  }
  if (node < N) {
    float* dst = (q < 2 ? sq : sk) + (size_t)(g * N + node) * 8 + (q & 1) * 4;
    *(float4v*)dst = (float4v){accq[0], accq[1], accq[2], accq[3]};
  }
}

// ---- 5a. bucket-level counts (LDS hist per block) ---------------------------
__global__ void __launch_bounds__(256) k_count(
    const int* __restrict__ d1, const int* __restrict__ d2,
    int* __restrict__ gcnt, int N, int E, int NB) {
  __shared__ int h[512];
  int tid = threadIdx.x;
  for (int i = tid; i < NB; i += 256) h[i] = 0;
  __syncthreads();
  int E2 = 2 * E;
  int e0 = blockIdx.x * 4096;
#pragma unroll
  for (int j = 0; j < 16; ++j) {
    int e = e0 + j * 256 + tid;
    if (e < E2) {
      int g = e >= E;
      int d = g ? d2[e - E] : d1[e];
      atomicAdd(&h[(g * N + d) >> 8], 1);
    }
  }
  __syncthreads();
  for (int i = tid; i < NB; i += 256)
    if (h[i]) atomicAdd(&gcnt[i], h[i]);
}

// ---- 5b. scan bucket totals -> bbase/bcur; offs[N2]=total -------------------
__global__ void k_bucket_scan(const int* __restrict__ gcnt, int* __restrict__ bbase,
                              int* __restrict__ bcur, int* __restrict__ offs,
                              int NB, int total, int N2) {
  __shared__ int sd[512];
  int tid = threadIdx.x;
  int v0 = (tid < NB) ? gcnt[tid] : 0;
  int v1 = (tid + 256 < NB) ? gcnt[tid + 256] : 0;
  sd[tid] = v0; sd[tid + 256] = v1;
  __syncthreads();
  for (int off = 1; off < 512; off <<= 1) {
    int t0 = (tid >= off) ? sd[tid - off] : 0;
    int t1 = (tid + 256 >= off) ? sd[tid + 256 - off] : 0;
    __syncthreads();
    sd[tid] += t0; sd[tid + 256] += t1;
    __syncthreads();
  }
  if (tid < NB) { int b = sd[tid] - v0; bbase[tid] = b; bcur[tid] = b; }
  if (tid + 256 < NB) { int b = sd[tid + 256] - v1; bbase[tid + 256] = b; bcur[tid + 256] = b; }
  if (tid == 0) { bbase[NB] = total; offs[N2] = total; }
}

// ---- 5c. bin edges into 256-node buckets (counting-sort per 4096-edge chunk)
__global__ void __launch_bounds__(256) k_bin(
    const int* __restrict__ ei1, const int* __restrict__ et1,
    const int* __restrict__ ei2, const int* __restrict__ et2,
    int* __restrict__ bcur, uint2* __restrict__ staged, int N, int E, int NB) {
  __shared__ int hist[512];
  __shared__ int basev[512];
  __shared__ int runstart[512];
  __shared__ unsigned sta[4096 * 2];  // 32 KB staging (dstg, srcet)
  int tid = threadIdx.x;
  int E2 = 2 * E;
  int e0 = blockIdx.x * 4096;
  int cnt2 = min(4096, E2 - e0);
  for (int i = tid; i < 512; i += 256) hist[i] = 0;
  __syncthreads();
  int dstg[16], srcet[16], rank[16];
#pragma unroll
  for (int j = 0; j < 16; ++j) {
    int e = e0 + j * 256 + tid;
    dstg[j] = -1;
    if (e < E2) {
      int g = e >= E;
      int el = e - (g ? E : 0);
      const int* ei = g ? ei2 : ei1;
      int s = ei[el], d = ei[E + el];
      int etv = (g ? et2 : et1)[el];
      dstg[j] = g * N + d;
      srcet[j] = (s << 3) | etv;
      rank[j] = atomicAdd(&hist[dstg[j] >> 8], 1);
    }
  }
  __syncthreads();
  basev[tid] = hist[tid];
  basev[tid + 256] = hist[tid + 256];
  __syncthreads();
  for (int off = 1; off < 512; off <<= 1) {
    int i0 = tid, i1 = tid + 256;
    int v0 = (i0 >= off) ? basev[i0 - off] : 0;
    int v1 = (i1 >= off) ? basev[i1 - off] : 0;
    __syncthreads();
    basev[i0] += v0; basev[i1] += v1;
    __syncthreads();
  }
  for (int i = tid; i < NB; i += 256)
    if (hist[i] > 0) runstart[i] = atomicAdd(&bcur[i], hist[i]);
  __syncthreads();
#pragma unroll
  for (int j = 0; j < 16; ++j)
    if (dstg[j] >= 0) {
      int b = dstg[j] >> 8;
      int slot = basev[b] - hist[b] + rank[j];
      sta[slot * 2] = (unsigned)dstg[j];
      sta[slot * 2 + 1] = (unsigned)srcet[j];
    }
  __syncthreads();
  for (int i = tid; i < cnt2; i += 256) {
    unsigned dg = sta[i * 2], se = sta[i * 2 + 1];
    int b = (int)(dg >> 8);
    int dest = runstart[b] + (i - (basev[b] - hist[b]));
    staged[dest] = make_uint2(dg, se);
  }
}

// ---- 5d. per-bucket: node-level offs + final sorted csr ---------------------
__global__ void __launch_bounds__(256) k_scatter2(
    const uint2* __restrict__ staged, const int* __restrict__ bbase,
    int* __restrict__ offs, int* __restrict__ csr, int N2) {
  __shared__ int hist[256];
  __shared__ int sd[256];
  __shared__ int cur[256];
  int b = blockIdx.x, tid = threadIdx.x;
  int nb0 = b << 8;
  int nnode = min(256, N2 - nb0);
  int s0 = bbase[b], s1 = bbase[b + 1];
  hist[tid] = 0;
  __syncthreads();
  for (int i = s0 + tid; i < s1; i += 256)
    atomicAdd(&hist[(int)staged[i].x - nb0], 1);
  __syncthreads();
  int v = hist[tid];
  sd[tid] = v; __syncthreads();
  for (int off = 1; off < 256; off <<= 1) {
    int t = (tid >= off) ? sd[tid - off] : 0;
    __syncthreads();
    sd[tid] += t;
    __syncthreads();
  }
  int ex = sd[tid] - v;  // exclusive scan
  if (tid < nnode) offs[nb0 + tid] = s0 + ex;
  cur[tid] = ex;
  __syncthreads();
  for (int i = s0 + tid; i < s1; i += 256) {
    uint2 en = staged[i];
    int node = (int)en.x - nb0;
    int sl = atomicAdd(&cur[node], 1);
    csr[s0 + sl] = (int)en.y;
  }
}

// ---- 6. fused aggregate: softmax + y[8][128] gather + K=1024 GEMM -----------
// Phase A (per wave, 4 nodes serial): softmax over incoming edges (as before),
// weight pass accumulates y[rel][2ch-of-lane] from xbf rows; rel is wave-
// uniform (readfirstlane) -> uniform switch, static register indices.
// Phase B: y -> LDS [16][1032] bf16; one barrier; MFMA GEMM out = y @ Wcat:
// A = Wb fragments (rows = out-ch), B = ylds (col = node), K = 1024.
// D: lane holds out[node = lane&15][ch = nt*16 + q*4 + reg] -> 16B stores.
#define ACC8(RELE, W, V)                                              \
  {                                                                   \
    int _r = __builtin_amdgcn_readfirstlane(RELE) & 7;                \
    float _lo = bflo(V), _hi = bfhi(V);                               \
    switch (_r) {                                                     \
      case 0: y[0][0] += (W) * _lo; y[0][1] += (W) * _hi; break;      \
      case 1: y[1][0] += (W) * _lo; y[1][1] += (W) * _hi; break;      \
      case 2: y[2][0] += (W) * _lo; y[2][1] += (W) * _hi; break;      \
      case 3: y[3][0] += (W) * _lo; y[3][1] += (W) * _hi; break;      \
      case 4: y[4][0] += (W) * _lo; y[4][1] += (W) * _hi; break;      \
      case 5: y[5][0] += (W) * _lo; y[5][1] += (W) * _hi; break;      \
      case 6: y[6][0] += (W) * _lo; y[6][1] += (W) * _hi; break;      \
      default: y[7][0] += (W) * _lo; y[7][1] += (W) * _hi; break;     \
    }                                                                 \
  }

__global__ void __launch_bounds__(256) k_aggregate(
    const int* __restrict__ csr, const int* __restrict__ offs,
    const float* __restrict__ sq, const float* __restrict__ sk,
    const u16* __restrict__ xbf, const u16* __restrict__ Wb,
    const float* __restrict__ bias, float* __restrict__ out,
    int N, int node_base) {
  __shared__ u16 ylds[16][1032];  // stride 1032 u16: bank-uniform b128 reads
  int wave = threadIdx.x >> 6, lane = threadIdx.x & 63;
  int q = lane >> 4, m16 = lane & 15;
  const char* xbfb = (const char*)xbf;

  for (int t = 0; t < 4; ++t) {
    int nl = blockIdx.x * 16 + wave * 4 + t;
    float y[8][2] = {{0.f, 0.f}, {0.f, 0.f}, {0.f, 0.f}, {0.f, 0.f},
                     {0.f, 0.f}, {0.f, 0.f}, {0.f, 0.f}, {0.f, 0.f}};
    if (nl < N) {
      int node = node_base + nl;
      int start = offs[node], end = offs[node + 1];
      const float* sqn = sq + (size_t)node * 8;

      float al[8]; int pl[8];
      float m = -INFINITY;
      {
        int c = 0;
        for (int i = start + lane; i < end; i += 64, ++c) {
          int p = csr[i]; int s = p >> 3, e = p & 7;
          float a = sqn[e] + sk[(size_t)(node_base + s) * 8 + e];
          a = (a > 0.f) ? a : 0.2f * a;
          if (c < 8) { al[c] = a; pl[c] = p; }
          m = fmaxf(m, a);
        }
      }
#pragma unroll
      for (int off = 32; off; off >>= 1) m = fmaxf(m, __shfl_xor(m, off));

      float ssum = 0.f;
      {
        int c = 0;
        for (int i = start + lane; i < end; i += 64, ++c) {
          float a;
          if (c < 8) a = al[c];
          else {
            int p = csr[i]; int s = p >> 3, e = p & 7;
            a = sqn[e] + sk[(size_t)(node_base + s) * 8 + e];
            a = (a > 0.f) ? a : 0.2f * a;
          }
          ssum += __expf(a - m);
        }
      }
#pragma unroll
      for (int off = 32; off; off >>= 1) ssum += __shfl_xor(ssum, off);
      float inv = 1.f / (ssum + 1e-16f);

      int c = 0;
      for (int base = start; base < end; base += 64, ++c) {
        int cnt = min(64, end - base);
        float w = 0.f; int p = 0;
        {
          int i = base + lane;
          if (i < end) {
            float a;
            if (c < 8) { p = pl[c]; a = al[c]; }
            else {
              p = csr[i]; int s = p >> 3, e = p & 7;
              a = sqn[e] + sk[(size_t)(node_base + s) * 8 + e];
              a = (a > 0.f) ? a : 0.2f * a;
            }
            w = __expf(a - m) * inv;
          }
        }
        int j = 0;
        for (; j + 3 < cnt; j += 4) {
          float w0 = __shfl(w, j), w1 = __shfl(w, j + 1),
                w2 = __shfl(w, j + 2), w3 = __shfl(w, j + 3);
          int p0 = __shfl(p, j), p1 = __shfl(p, j + 1),
              p2 = __shfl(p, j + 2), p3 = __shfl(p, j + 3);
          unsigned v0 = *(const unsigned*)(xbfb + (((size_t)(unsigned)(p0 >> 3)) << 8) + lane * 4);
          unsigned v1 = *(const unsigned*)(xbfb + (((size_t)(unsigned)(p1 >> 3)) << 8) + lane * 4);
          unsigned v2 = *(const unsigned*)(xbfb + (((size_t)(unsigned)(p2 >> 3)) << 8) + lane * 4);
          unsigned v3 = *(const unsigned*)(xbfb + (((size_t)(unsigned)(p3 >> 3)) << 8) + lane * 4);
          ACC8(p0, w0, v0);
          ACC8(p1, w1, v1);
          ACC8(p2, w2, v2);
          ACC8(p3, w3, v3);
        }
        for (; j < cnt; ++j) {
          float w0 = __shfl(w, j);
          int p0 = __shfl(p, j);
          unsigned v0 = *(const unsigned*)(xbfb + (((size_t)(unsigned)(p0 >> 3)) << 8) + lane * 4);
          ACC8(p0, w0, v0);
        }
      }
    }
    // dump y -> ylds[node][r*128 + 2*lane] (bf16 pair, b32; 2-way banks = free)
    int nrow = wave * 4 + t;
#pragma unroll
    for (int r = 0; r < 8; ++r) {
      unsigned pk = (unsigned)f2bf(y[r][0]) | ((unsigned)f2bf(y[r][1]) << 16);
      *(unsigned*)&ylds[nrow][r * 128 + lane * 2] = pk;
    }
  }
  __syncthreads();

  // GEMM: wave handles out-ch tiles nt = {2*wave, 2*wave+1}, K = 1024
  floatx4 acc0 = (floatx4){0.f, 0.f, 0.f, 0.f};
  floatx4 acc1 = (floatx4){0.f, 0.f, 0.f, 0.f};
  int nt0 = wave * 2, nt1 = wave * 2 + 1;
#pragma unroll
  for (int kk = 0; kk < 32; ++kk) {
    short8 b = *(const short8*)&ylds[m16][kk * 32 + q * 8];
    short8 a0 = *(const short8*)(Wb + ((size_t)(kk * 8 + nt0)) * 512 + lane * 8);
    short8 a1 = *(const short8*)(Wb + ((size_t)(kk * 8 + nt1)) * 512 + lane * 8);
    acc0 = __builtin_amdgcn_mfma_f32_16x16x32_bf16(a0, b, acc0, 0, 0, 0);
    acc1 = __builtin_amdgcn_mfma_f32_16x16x32_bf16(a1, b, acc1, 0, 0, 0);
  }
  int onode = blockIdx.x * 16 + m16;
  if (onode < N) {
    float* op = out + (size_t)onode * 128;
    int ch0 = nt0 * 16 + q * 4, ch1 = nt1 * 16 + q * 4;
    float4v bv0 = *(const float4v*)(bias + ch0);
    float4v bv1 = *(const float4v*)(bias + ch1);
    float4v o0 = (float4v){fmaxf(acc0[0] + bv0.x, 0.f), fmaxf(acc0[1] + bv0.y, 0.f),
                           fmaxf(acc0[2] + bv0.z, 0.f), fmaxf(acc0[3] + bv0.w, 0.f)};
    float4v o1 = (float4v){fmaxf(acc1[0] + bv1.x, 0.f), fmaxf(acc1[1] + bv1.y, 0.f),
                           fmaxf(acc1[2] + bv1.z, 0.f), fmaxf(acc1[3] + bv1.w, 0.f)};
    *(float4v*)(op + ch0) = o0;
    *(float4v*)(op + ch1) = o1;
  }
}

// -----------------------------------------------------------------------------
extern "C" void kernel_launch(void* const* d_in, const int* in_sizes, int n_in,
                              void* d_out, int out_size, void* d_ws, size_t ws_size,
                              hipStream_t stream) {
  const float* x1 = (const float*)d_in[0];
  const int* ei1 = (const int*)d_in[1];
  const int* et1 = (const int*)d_in[2];
  const float* x2 = (const float*)d_in[3];
  const int* ei2 = (const int*)d_in[4];
  const int* et2 = (const int*)d_in[5];
  const float* W1 = (const float*)d_in[6];
  const float* q1 = (const float*)d_in[7];
  const float* k1 = (const float*)d_in[8];
  const float* b1 = (const float*)d_in[9];
  const float* W2 = (const float*)d_in[10];
  const float* q2 = (const float*)d_in[11];
  const float* k2 = (const float*)d_in[12];
  const float* b2 = (const float*)d_in[13];

  const int N = in_sizes[0] / 128;
  const int E = in_sizes[1] / 2;
  const int R = in_sizes[6] / (128 * 128);
  const int KK = R * 4;
  const int N2 = 2 * N;
  const int NB = (N2 + 255) >> 8;           // 256-node buckets (<=512)

  size_t off = 0;
  char* w = (char*)d_ws;
  auto carve = [&](size_t bytes) -> void* {
    void* p = w + off;
    off += (bytes + 255) & ~(size_t)255;
    return p;
  };
  u16* Wb = (u16*)carve((size_t)2 * KK * 4096 * 2);
  u16* Bqk = (u16*)carve((size_t)2 * 4 * 64 * 8 * 2);
  float* Wq = (float*)carve((size_t)2 * R * 128 * 4);
  float* Wk = (float*)carve((size_t)2 * R * 128 * 4);
  u16* xbf = (u16*)carve((size_t)N2 * 128 * 2);         // 25.6MB, both graphs
  float* sq = (float*)carve((size_t)N2 * 8 * 4);
  float* sk = (float*)carve((size_t)N2 * 8 * 4);
  int* offs = (int*)carve((size_t)(N2 + 1) * 4);
  int* gcnt = (int*)carve(512 * 4);
  int* bbase = (int*)carve(520 * 4);
  int* bcur = (int*)carve(512 * 4);
  uint2* staged = (uint2*)carve((size_t)2 * E * 8);
  int* csr = (int*)carve((size_t)2 * E * 4);
  if (off > ws_size) return;

  const int nbin = (2 * E + 4095) / 4096;

  hipMemsetAsync(gcnt, 0, 512 * 4, stream);
  k_prep_wb<<<dim3((KK * 512 + 255) / 256, 2), dim3(256), 0, stream>>>(W1, W2, Wb, KK);
  k_prep_wqk<<<dim3((2 * R * 128 * 64 + 255) / 256), dim3(256), 0, stream>>>(
      W1, q1, k1, W2, q2, k2, Wq, Wk, R * 128);
  k_prep_bqk<<<dim3(1), dim3(256), 0, stream>>>(Wq, Wk, Bqk, R);
  k_sqk<<<dim3((N + 63) / 64, 2), dim3(256), 0, stream>>>(x1, x2, Bqk, xbf, sq, sk, N);
  k_count<<<dim3(nbin), dim3(256), 0, stream>>>(ei1 + E, ei2 + E, gcnt, N, E, NB);
  k_bucket_scan<<<dim3(1), dim3(256), 0, stream>>>(gcnt, bbase, bcur, offs, NB, 2 * E, N2);
  k_bin<<<dim3(nbin), dim3(256), 0, stream>>>(ei1, et1, ei2, et2, bcur, staged, N, E, NB);
  k_scatter2<<<dim3(NB), dim3(256), 0, stream>>>(staged, bbase, offs, csr, N2);

  for (int g = 0; g < 2; ++g) {
    const float* bv = g ? b2 : b1;
    float* outp = (float*)d_out + (size_t)g * N * 128;
    k_aggregate<<<dim3((N + 15) / 16), dim3(256), 0, stream>>>(
        csr, offs, sq, sk, xbf + (size_t)g * N * 128, Wb + (size_t)g * KK * 4096,
        bv, outp, N, g * N);
  }
}